// Round 5
// baseline (450.182 us; speedup 1.0000x reference)
//
#include <hip/hip_runtime.h>
#include <hip/hip_fp16.h>

// ScaledDotProductAttention: context = softmax(QK^T/sqrt(d) - 100*mask) @ V
// B=32 Tq=2048 Tk=1024 d=128 dv=256, fp32 in/out.
// R5: barrier-free hot loops. Pre-kernels stage K (fp16) and V^T (fp16,
// [dv][k]) in d_ws so all MFMA fragments are contiguous 16B/lane global loads
// (L2-resident per XCD). LDS holds only P (32x1024 f16) + rowsum. 3 barriers
// total per wg (rowsum reduce) vs ~96 in R1-R4 — no more per-step
// vmcnt(0)+barrier drains.

namespace {

constexpr int kB = 32, kTq = 2048, kTk = 1024, kD = 128, kDv = 256;
constexpr int kBQ = 32;   // q rows per workgroup
constexpr float kScale = 0.08838834764831845f;  // 1/sqrt(128)

typedef _Float16 half8 __attribute__((ext_vector_type(8)));
typedef _Float16 half4 __attribute__((ext_vector_type(4)));
typedef float    f32x4 __attribute__((ext_vector_type(4)));

// workspace layout
constexpr size_t kWsK = 0;                       // K16 [32][1024][128] f16 = 8 MiB
constexpr size_t kWsV = 8388608;                 // VT  [32][256][1024] f16 = 16 MiB
constexpr size_t kWsNeed = kWsV + 16777216;

// LDS: P [32 q][1024 k] f16 swizzled (65536) + rowsum[32] f32
constexpr int kOffSum = 65536;
constexpr int kLds    = 65664;

__device__ __forceinline__ int pswz(int row, int cb) {  // row<32, cb<2048 (bytes)
  return row * 2048 + (cb ^ ((row & 7) << 4));
}

// ---- pre-kernel 1: K f32 -> f16 (elementwise) ----
__global__ __launch_bounds__(256)
void cvt_k(const float* __restrict__ in, _Float16* __restrict__ out) {
  int i = (blockIdx.x * 256 + threadIdx.x) * 8;
  f32x4 a = *(const f32x4*)(in + i);
  f32x4 b = *(const f32x4*)(in + i + 4);
  half8 h;
  h[0] = a[0]; h[1] = a[1]; h[2] = a[2]; h[3] = a[3];
  h[4] = b[0]; h[5] = b[1]; h[6] = b[2]; h[7] = b[3];
  *(half8*)(out + i) = h;
}

// ---- pre-kernel 2: V [k][dv] f32 -> V^T [dv][k] f16 (64x64 LDS tiles) ----
__global__ __launch_bounds__(256)
void trans_v(const float* __restrict__ v, _Float16* __restrict__ vt) {
  __shared__ _Float16 t[64 * 66];                // pad 2 -> conflict-light
  const int b   = blockIdx.x >> 6;
  const int idx = blockIdx.x & 63;
  const int k0  = (idx & 15) * 64;
  const int d0  = (idx >> 4) * 64;
  const int r = threadIdx.x >> 6, c = threadIdx.x & 63;
#pragma unroll 4
  for (int it = 0; it < 16; ++it) {
    float x = v[((size_t)b * kTk + k0 + it * 4 + r) * kDv + d0 + c];
    t[c * 66 + it * 4 + r] = (_Float16)x;
  }
  __syncthreads();
  const int dr = threadIdx.x >> 4, kc = (threadIdx.x & 15) * 4;
#pragma unroll
  for (int it = 0; it < 4; ++it) {
    int drow = it * 16 + dr;
    half4 h;
#pragma unroll
    for (int j = 0; j < 4; ++j) h[j] = t[drow * 66 + kc + j];
    *(half4*)(vt + ((size_t)b * kDv + d0 + drow) * kTk + k0 + kc) = h;
  }
}

// ---- main kernel ----
__global__ __launch_bounds__(512, 4)
void attn_main(const float* __restrict__ qg, const _Float16* __restrict__ K16,
               const _Float16* __restrict__ VT, const float* __restrict__ mg,
               float* __restrict__ out) {
  __shared__ __align__(16) unsigned char s_[kLds];
  float* rowsum = (float*)(s_ + kOffSum);

  const int tid  = threadIdx.x;
  const int lane = tid & 63;
  const int wid  = tid >> 6;     // 0..7
  const int l15  = lane & 15;
  const int lg   = lane >> 4;    // 0..3

  // XCD mapping: each XCD works one batch at a time (K/V^T stay L2-resident)
  const int bi    = blockIdx.x;               // 0..2047
  const int batch = (bi & 7) * 4 + (bi >> 9);
  const int q0    = ((bi >> 3) & 63) * kBQ;

  const float* Q = qg + ((size_t)batch * kTq + q0) * kD;
  const _Float16* Kb = K16 + (size_t)batch * kTk * kD;
  const _Float16* Vb = VT + (size_t)batch * kDv * kTk;
  const float* M = mg + ((size_t)batch * kTq + q0) * kTk;
  float* CTX = out + ((size_t)batch * kTq + q0) * kDv;
  float* SCR = out + (size_t)kB * kTq * kDv + ((size_t)batch * kTq + q0) * kTk;

  if (tid < kBQ) rowsum[tid] = 0.f;   // ordered by the post-phase-1 barrier

  const int wr = wid >> 2;   // 0..1 : q row group (16 rows)
  const int wc = wid & 3;    // 0..3 : key group (QK^T) / dv group (PV)

  // ---- Q fragments (16 rows x 128 d per wave) ----
  half8 qf[4];
  {
    const float* qrow = Q + (size_t)(wr * 16 + l15) * kD + lg * 8;
#pragma unroll
    for (int c = 0; c < 4; ++c) {
      f32x4 a = *(const f32x4*)(qrow + c * 32);
      f32x4 b = *(const f32x4*)(qrow + c * 32 + 4);
      half8 h;
      h[0] = a[0]; h[1] = a[1]; h[2] = a[2]; h[3] = a[3];
      h[4] = b[0]; h[5] = b[1]; h[6] = b[2]; h[7] = b[3];
      qf[c] = h;
    }
  }

  // ===== Phase 1: S=QK^T, e=exp -> P(LDS), rowsums. NO barriers. =====
  float mv[4], mvN[4];
#pragma unroll
  for (int j = 0; j < 4; ++j)
    mv[j] = M[(size_t)(wr * 16 + lg * 4 + j) * kTk + wc * 16 + l15];

  float rsum[4] = {0.f, 0.f, 0.f, 0.f};
  constexpr int kSteps = kTk / 64;   // 16
#pragma unroll 2
  for (int step = 0; step < kSteps; ++step) {
    if (step + 1 < kSteps) {          // mask prefetch (lands during MFMA/exp)
#pragma unroll
      for (int j = 0; j < 4; ++j)
        mvN[j] = M[(size_t)(wr * 16 + lg * 4 + j) * kTk +
                   (step + 1) * 64 + wc * 16 + l15];
    }
    const _Float16* krow = Kb + (size_t)(step * 64 + wc * 16 + l15) * kD + lg * 8;
    half8 bf0 = *(const half8*)(krow);
    half8 bf1 = *(const half8*)(krow + 32);
    half8 bf2 = *(const half8*)(krow + 64);
    half8 bf3 = *(const half8*)(krow + 96);
    f32x4 acc = {0.f, 0.f, 0.f, 0.f};
    __builtin_amdgcn_s_setprio(1);
    acc = __builtin_amdgcn_mfma_f32_16x16x32_f16(qf[0], bf0, acc, 0, 0, 0);
    acc = __builtin_amdgcn_mfma_f32_16x16x32_f16(qf[1], bf1, acc, 0, 0, 0);
    acc = __builtin_amdgcn_mfma_f32_16x16x32_f16(qf[2], bf2, acc, 0, 0, 0);
    acc = __builtin_amdgcn_mfma_f32_16x16x32_f16(qf[3], bf3, acc, 0, 0, 0);
    __builtin_amdgcn_s_setprio(0);
#pragma unroll
    for (int j = 0; j < 4; ++j) {
      float e = __expf(acc[j] * kScale - 100.f * mv[j]);
      rsum[j] += e;
      *(_Float16*)(s_ + pswz(wr * 16 + lg * 4 + j,
                             (step * 64 + wc * 16 + l15) * 2)) = (_Float16)e;
    }
#pragma unroll
    for (int j = 0; j < 4; ++j) mv[j] = mvN[j];
  }

  // ===== Phase 2: rowsum reduce (the only barriers) =====
  __syncthreads();
#pragma unroll
  for (int m = 1; m <= 8; m <<= 1)
#pragma unroll
    for (int j = 0; j < 4; ++j) rsum[j] += __shfl_xor(rsum[j], m);
  if (l15 == 0) {
#pragma unroll
    for (int j = 0; j < 4; ++j)
      atomicAdd(&rowsum[wr * 16 + lg * 4 + j], rsum[j]);
  }
  __syncthreads();
  if (tid < kBQ) rowsum[tid] = 1.0f / rowsum[tid];
  __syncthreads();

  // ===== Phase 3: normalized score write (coalesced f32x4) =====
#pragma unroll
  for (int rr = 0; rr < 4; ++rr) {
    int row = wid * 4 + rr;
    float inv = rowsum[row];
#pragma unroll
    for (int it = 0; it < 4; ++it) {
      int col = it * 256 + lane * 4;
      half4 hv = *(const half4*)(s_ + pswz(row, col * 2));
      f32x4 o;
      o[0] = (float)hv[0] * inv; o[1] = (float)hv[1] * inv;
      o[2] = (float)hv[2] * inv; o[3] = (float)hv[3] * inv;
      *(f32x4*)(SCR + (size_t)row * kTk + col) = o;
    }
  }

  // ===== Phase 4: context = (P @ V) * inv. NO barriers (V^T from L2). =====
  f32x4 acc4[4];
#pragma unroll
  for (int t = 0; t < 4; ++t) acc4[t] = (f32x4){0, 0, 0, 0};

#pragma unroll 2
  for (int kc = 0; kc < kTk / 32; ++kc) {   // 32 chunks of K=32
    half8 af = *(const half8*)(s_ + pswz(wr * 16 + l15, kc * 64 + lg * 16));
    __builtin_amdgcn_s_setprio(1);
#pragma unroll
    for (int t = 0; t < 4; ++t) {
      half8 bf = *(const half8*)(Vb + (size_t)(wc * 64 + t * 16 + l15) * kTk +
                                 kc * 32 + lg * 8);
      acc4[t] = __builtin_amdgcn_mfma_f32_16x16x32_f16(af, bf, acc4[t], 0, 0, 0);
    }
    __builtin_amdgcn_s_setprio(0);
  }

  float invr[4];
#pragma unroll
  for (int j = 0; j < 4; ++j) invr[j] = rowsum[wr * 16 + lg * 4 + j];
#pragma unroll
  for (int t = 0; t < 4; ++t)
#pragma unroll
    for (int j = 0; j < 4; ++j)
      CTX[(size_t)(wr * 16 + lg * 4 + j) * kDv + wc * 64 + t * 16 + l15] =
          acc4[t][j] * invr[j];
}

}  // namespace

extern "C" void kernel_launch(void* const* d_in, const int* in_sizes, int n_in,
                              void* d_out, int out_size, void* d_ws, size_t ws_size,
                              hipStream_t stream) {
  const float* q = (const float*)d_in[0];
  const float* k = (const float*)d_in[1];
  const float* v = (const float*)d_in[2];
  const float* m = (const float*)d_in[3];
  float* out = (float*)d_out;
  (void)in_sizes; (void)n_in; (void)out_size; (void)ws_size;

  _Float16* k16 = (_Float16*)((char*)d_ws + kWsK);
  _Float16* vt  = (_Float16*)((char*)d_ws + kWsV);

  // stage K (fp16) and V^T (fp16) into workspace
  hipLaunchKernelGGL(cvt_k, dim3(kB * kTk * kD / (256 * 8)), dim3(256), 0, stream,
                     k, k16);
  hipLaunchKernelGGL(trans_v, dim3(kB * 64), dim3(256), 0, stream, v, vt);

  dim3 grid(kB * (kTq / kBQ));   // 2048 workgroups
  dim3 block(512);
  hipLaunchKernelGGL(attn_main, grid, block, 0, stream, q, k16, vt, m, out);
}

// Round 6
// 428.520 us; speedup vs baseline: 1.0506x; 1.0506x over previous
//
#include <hip/hip_runtime.h>
#include <hip/hip_fp16.h>

// ScaledDotProductAttention: context = softmax(QK^T/sqrt(d) - 100*mask) @ V
// B=32 Tq=2048 Tk=1024 d=128 dv=256, fp32 in/out.
// R6: mask decoupled from the MFMA loop. Phase 1: pure QK^T (K16 fragments
// direct from L2, 2-deep ping-pong prefetch, NO barriers, NO HBM in the vmcnt
// queue), stores raw logits*scale fp16 into P (LDS). Phase 2: wave-local
// streaming — coalesced mask f32x4 loads + exp + rowsum (shfl) + normalized
// score writes, zero barriers. Phase 4: PV with V^T fp16 from L2 (d_ws),
// 2-deep prefetch. 2 barriers total per workgroup.

namespace {

constexpr int kB = 32, kTq = 2048, kTk = 1024, kD = 128, kDv = 256;
constexpr int kBQ = 32;   // q rows per workgroup
constexpr float kScale = 0.08838834764831845f;  // 1/sqrt(128)

typedef _Float16 half8 __attribute__((ext_vector_type(8)));
typedef _Float16 half4 __attribute__((ext_vector_type(4)));
typedef float    f32x4 __attribute__((ext_vector_type(4)));

// workspace layout
constexpr size_t kWsK = 0;          // K16 [32][1024][128] f16 = 8 MiB
constexpr size_t kWsV = 8388608;    // VT  [32][256][1024] f16 = 16 MiB

// LDS: P [32 q][1024 k] f16 swizzled (65536) + rowsum[32] f32
constexpr int kOffSum = 65536;
constexpr int kLds    = 65536 + 128;

__device__ __forceinline__ int pswz(int row, int cb) {  // row<32, cb<2048 bytes
  return row * 2048 + (cb ^ ((row & 7) << 4));
}

struct Frag4 { half8 a, b, c, d; };

// ---- pre-kernel 1: K f32 -> f16 (elementwise; R5-proven) ----
__global__ __launch_bounds__(256)
void cvt_k(const float* __restrict__ in, _Float16* __restrict__ out) {
  int i = (blockIdx.x * 256 + threadIdx.x) * 8;
  f32x4 a = *(const f32x4*)(in + i);
  f32x4 b = *(const f32x4*)(in + i + 4);
  half8 h;
  h[0] = a[0]; h[1] = a[1]; h[2] = a[2]; h[3] = a[3];
  h[4] = b[0]; h[5] = b[1]; h[6] = b[2]; h[7] = b[3];
  *(half8*)(out + i) = h;
}

// ---- pre-kernel 2: V [k][dv] f32 -> V^T [dv][k] f16 (R5-proven) ----
__global__ __launch_bounds__(256)
void trans_v(const float* __restrict__ v, _Float16* __restrict__ vt) {
  __shared__ _Float16 t[64 * 66];
  const int b   = blockIdx.x >> 6;
  const int idx = blockIdx.x & 63;
  const int k0  = (idx & 15) * 64;
  const int d0  = (idx >> 4) * 64;
  const int r = threadIdx.x >> 6, c = threadIdx.x & 63;
#pragma unroll 4
  for (int it = 0; it < 16; ++it) {
    float x = v[((size_t)b * kTk + k0 + it * 4 + r) * kDv + d0 + c];
    t[c * 66 + it * 4 + r] = (_Float16)x;
  }
  __syncthreads();
  const int dr = threadIdx.x >> 4, kc = (threadIdx.x & 15) * 4;
#pragma unroll
  for (int it = 0; it < 4; ++it) {
    int drow = it * 16 + dr;
    half4 h;
#pragma unroll
    for (int j = 0; j < 4; ++j) h[j] = t[drow * 66 + kc + j];
    *(half4*)(vt + ((size_t)b * kDv + d0 + drow) * kTk + k0 + kc) = h;
  }
}

// ---- main kernel ----
__global__ __launch_bounds__(512, 4)
void attn_main(const float* __restrict__ qg, const _Float16* __restrict__ K16,
               const _Float16* __restrict__ VT, const float* __restrict__ mg,
               float* __restrict__ out) {
  __shared__ __align__(16) unsigned char s_[kLds];
  float* rowsum = (float*)(s_ + kOffSum);

  const int tid  = threadIdx.x;
  const int lane = tid & 63;
  const int wid  = tid >> 6;     // 0..7
  const int l15  = lane & 15;
  const int lg   = lane >> 4;    // 0..3

  // XCD mapping: each XCD works one batch at a time (K16/VT stay L2-resident)
  const int bi    = blockIdx.x;               // 0..2047
  const int batch = (bi & 7) * 4 + (bi >> 9);
  const int q0    = ((bi >> 3) & 63) * kBQ;

  const float* Q = qg + ((size_t)batch * kTq + q0) * kD;
  const _Float16* Kb = K16 + (size_t)batch * kTk * kD;
  const _Float16* Vb = VT + (size_t)batch * kDv * kTk;
  const float* M = mg + ((size_t)batch * kTq + q0) * kTk;
  float* CTX = out + ((size_t)batch * kTq + q0) * kDv;
  float* SCR = out + (size_t)kB * kTq * kDv + ((size_t)batch * kTq + q0) * kTk;

  const int wr = wid >> 2;   // 0..1 : q row group (16 rows)
  const int wc = wid & 3;    // 0..3 : key group (QK^T) / dv group (PV)

  // ---- Q fragments (16 rows x 128 d per wave) ----
  half8 qf0, qf1, qf2, qf3;
  {
    const float* qrow = Q + (size_t)(wr * 16 + l15) * kD + lg * 8;
    f32x4 a, b; half8 h;
    a = *(const f32x4*)(qrow);       b = *(const f32x4*)(qrow + 4);
    h[0]=a[0];h[1]=a[1];h[2]=a[2];h[3]=a[3];h[4]=b[0];h[5]=b[1];h[6]=b[2];h[7]=b[3];
    qf0 = h;
    a = *(const f32x4*)(qrow + 32);  b = *(const f32x4*)(qrow + 36);
    h[0]=a[0];h[1]=a[1];h[2]=a[2];h[3]=a[3];h[4]=b[0];h[5]=b[1];h[6]=b[2];h[7]=b[3];
    qf1 = h;
    a = *(const f32x4*)(qrow + 64);  b = *(const f32x4*)(qrow + 68);
    h[0]=a[0];h[1]=a[1];h[2]=a[2];h[3]=a[3];h[4]=b[0];h[5]=b[1];h[6]=b[2];h[7]=b[3];
    qf2 = h;
    a = *(const f32x4*)(qrow + 96);  b = *(const f32x4*)(qrow + 100);
    h[0]=a[0];h[1]=a[1];h[2]=a[2];h[3]=a[3];h[4]=b[0];h[5]=b[1];h[6]=b[2];h[7]=b[3];
    qf3 = h;
  }

  // ===== Phase 1: S=QK^T -> P holds s*scale (fp16). Barrier-free. =====
  auto ldK = [&](int step) -> Frag4 {
    const _Float16* p = Kb + (size_t)(step * 64 + wc * 16 + l15) * kD + lg * 8;
    Frag4 f;
    f.a = *(const half8*)(p);
    f.b = *(const half8*)(p + 32);
    f.c = *(const half8*)(p + 64);
    f.d = *(const half8*)(p + 96);
    return f;
  };
  auto qk = [&](const Frag4& f) -> f32x4 {
    f32x4 acc = {0.f, 0.f, 0.f, 0.f};
    acc = __builtin_amdgcn_mfma_f32_16x16x32_f16(qf0, f.a, acc, 0, 0, 0);
    acc = __builtin_amdgcn_mfma_f32_16x16x32_f16(qf1, f.b, acc, 0, 0, 0);
    acc = __builtin_amdgcn_mfma_f32_16x16x32_f16(qf2, f.c, acc, 0, 0, 0);
    acc = __builtin_amdgcn_mfma_f32_16x16x32_f16(qf3, f.d, acc, 0, 0, 0);
    return acc;
  };
  auto stP = [&](f32x4 acc, int step) {
    int colb = (step * 64 + wc * 16 + l15) * 2;
#pragma unroll
    for (int j = 0; j < 4; ++j)
      *(_Float16*)(s_ + pswz(wr * 16 + lg * 4 + j, colb)) =
          (_Float16)(acc[j] * kScale);
  };

  Frag4 fA = ldK(0), fB = ldK(1);
  for (int s = 0; s < 16; s += 2) {
    __builtin_amdgcn_s_setprio(1);
    f32x4 a0 = qk(fA);
    __builtin_amdgcn_s_setprio(0);
    if (s + 2 < 16) fA = ldK(s + 2);
    stP(a0, s);
    __builtin_amdgcn_s_setprio(1);
    f32x4 a1 = qk(fB);
    __builtin_amdgcn_s_setprio(0);
    if (s + 3 < 16) fB = ldK(s + 3);
    stP(a1, s + 1);
  }
  __syncthreads();   // barrier #1: all of P(s) published

  // ===== Phase 2: mask stream + exp + rowsum + normalized score. =====
  // Wave-local: wave w owns rows 4w..4w+3; lane group (l>>4) -> row,
  // l15 -> col slice. Fully coalesced mask loads, no barriers, no atomics.
  {
    const int prow  = wid * 4 + (lane >> 4);
    const int pcol0 = l15 * 4;
    const float* mrow = M + (size_t)prow * kTk + pcol0;
    float rs = 0.f;
#pragma unroll 4
    for (int it = 0; it < 16; ++it) {
      f32x4 mv = *(const f32x4*)(mrow + it * 64);
      int ab = pswz(prow, (pcol0 + it * 64) * 2);
      half4 sv = *(const half4*)(s_ + ab);
      float e0 = __expf((float)sv[0] - 100.f * mv[0]);
      float e1 = __expf((float)sv[1] - 100.f * mv[1]);
      float e2 = __expf((float)sv[2] - 100.f * mv[2]);
      float e3 = __expf((float)sv[3] - 100.f * mv[3]);
      rs += (e0 + e1) + (e2 + e3);
      half4 ev; ev[0] = e0; ev[1] = e1; ev[2] = e2; ev[3] = e3;
      *(half4*)(s_ + ab) = ev;
    }
    rs += __shfl_xor(rs, 1); rs += __shfl_xor(rs, 2);
    rs += __shfl_xor(rs, 4); rs += __shfl_xor(rs, 8);
    float inv = 1.f / rs;
    if (l15 == 0) rowsum[prow] = inv;   // for phase-4 epilogue (cross-wave)
    float* srow = SCR + (size_t)prow * kTk + pcol0;
#pragma unroll 4
    for (int it = 0; it < 16; ++it) {
      half4 ev = *(const half4*)(s_ + pswz(prow, (pcol0 + it * 64) * 2));
      f32x4 o;
      o[0] = (float)ev[0] * inv; o[1] = (float)ev[1] * inv;
      o[2] = (float)ev[2] * inv; o[3] = (float)ev[3] * inv;
      *(f32x4*)(srow + it * 64) = o;
    }
  }
  __syncthreads();   // barrier #2: P(e) + rowsum published for PV

  // ===== Phase 4: context = (P @ V^T) * inv. Barrier-free, 2-deep. =====
  auto ldP = [&](int kc) -> half8 {
    return *(const half8*)(s_ + pswz(wr * 16 + l15, kc * 64 + lg * 16));
  };
  auto ldV = [&](int kc) -> Frag4 {
    const _Float16* p = Vb + (size_t)(wc * 64 + l15) * kTk + kc * 32 + lg * 8;
    Frag4 f;
    f.a = *(const half8*)(p);
    f.b = *(const half8*)(p + (size_t)16 * kTk);
    f.c = *(const half8*)(p + (size_t)32 * kTk);
    f.d = *(const half8*)(p + (size_t)48 * kTk);
    return f;
  };

  f32x4 c0 = {0,0,0,0}, c1 = {0,0,0,0}, c2 = {0,0,0,0}, c3 = {0,0,0,0};
  half8 pA = ldP(0); Frag4 vA = ldV(0);
  half8 pB = ldP(1); Frag4 vB = ldV(1);
  for (int kc = 0; kc < 32; kc += 2) {
    __builtin_amdgcn_s_setprio(1);
    c0 = __builtin_amdgcn_mfma_f32_16x16x32_f16(pA, vA.a, c0, 0, 0, 0);
    c1 = __builtin_amdgcn_mfma_f32_16x16x32_f16(pA, vA.b, c1, 0, 0, 0);
    c2 = __builtin_amdgcn_mfma_f32_16x16x32_f16(pA, vA.c, c2, 0, 0, 0);
    c3 = __builtin_amdgcn_mfma_f32_16x16x32_f16(pA, vA.d, c3, 0, 0, 0);
    __builtin_amdgcn_s_setprio(0);
    if (kc + 2 < 32) { pA = ldP(kc + 2); vA = ldV(kc + 2); }
    __builtin_amdgcn_s_setprio(1);
    c0 = __builtin_amdgcn_mfma_f32_16x16x32_f16(pB, vB.a, c0, 0, 0, 0);
    c1 = __builtin_amdgcn_mfma_f32_16x16x32_f16(pB, vB.b, c1, 0, 0, 0);
    c2 = __builtin_amdgcn_mfma_f32_16x16x32_f16(pB, vB.c, c2, 0, 0, 0);
    c3 = __builtin_amdgcn_mfma_f32_16x16x32_f16(pB, vB.d, c3, 0, 0, 0);
    __builtin_amdgcn_s_setprio(0);
    if (kc + 3 < 32) { pB = ldP(kc + 3); vB = ldV(kc + 3); }
  }

  // epilogue: scale by 1/rowsum, store context
  float ivr[4];
#pragma unroll
  for (int j = 0; j < 4; ++j) ivr[j] = rowsum[wr * 16 + lg * 4 + j];
#pragma unroll
  for (int j = 0; j < 4; ++j) {
    size_t r = (size_t)(wr * 16 + lg * 4 + j) * kDv + wc * 64 + l15;
    CTX[r]      = c0[j] * ivr[j];
    CTX[r + 16] = c1[j] * ivr[j];
    CTX[r + 32] = c2[j] * ivr[j];
    CTX[r + 48] = c3[j] * ivr[j];
  }
}

}  // namespace

extern "C" void kernel_launch(void* const* d_in, const int* in_sizes, int n_in,
                              void* d_out, int out_size, void* d_ws, size_t ws_size,
                              hipStream_t stream) {
  const float* q = (const float*)d_in[0];
  const float* k = (const float*)d_in[1];
  const float* v = (const float*)d_in[2];
  const float* m = (const float*)d_in[3];
  float* out = (float*)d_out;
  (void)in_sizes; (void)n_in; (void)out_size; (void)ws_size;

  _Float16* k16 = (_Float16*)((char*)d_ws + kWsK);
  _Float16* vt  = (_Float16*)((char*)d_ws + kWsV);

  hipLaunchKernelGGL(cvt_k, dim3(kB * kTk * kD / (256 * 8)), dim3(256), 0, stream,
                     k, k16);
  hipLaunchKernelGGL(trans_v, dim3(kB * 64), dim3(256), 0, stream, v, vt);

  dim3 grid(kB * (kTq / kBQ));   // 2048 workgroups
  dim3 block(512);
  hipLaunchKernelGGL(attn_main, grid, block, 0, stream, q, k16, vt, m, out);
}